// Round 2
// baseline (655.937 us; speedup 1.0000x reference)
//
#include <hip/hip_runtime.h>
#include <hip/hip_bf16.h>
#include <math.h>

typedef __hip_bfloat16 bf16;

__device__ __forceinline__ float b2f(bf16 v){ return __bfloat162float(v); }
__device__ __forceinline__ float eluf(float x){ return x > 0.f ? x : __expf(x) - 1.f; }
__device__ __forceinline__ float lrelu(float x){ return x > 0.f ? x : 0.2f * x; }

// ---------------- dtype detection ----------------
// Interpret first n halves of x as bf16. True bf16 N(0,1) data never has
// exponent field >= 0xC6 (|v| >= 2^71). fp32 data misread as bf16 hits that
// with ~23% probability per element. flag: 0 = bf16 inputs, 1 = fp32 inputs.
__global__ void detect_k(const unsigned short* __restrict__ u16, int n, int* __restrict__ flag){
  int bad = 0;
  for (int k = threadIdx.x; k < n; k += 256){
    int ex = (u16[k] >> 7) & 0xFF;
    if (ex >= 0xC6) bad = 1;
  }
  if (__any(bad) && (threadIdx.x & 63) == 0) atomicOr(flag, 1);
}

// ---------------- unified input conversion to fp32 ----------------
struct ConvDesc {
  const void* src[21];
  int off[22];
};

__global__ void convert_all_k(ConvDesc d, float* __restrict__ out,
                              const int* __restrict__ flag, int total){
  int i = blockIdx.x * blockDim.x + threadIdx.x;
  if (i >= total) return;
  int a = 0;
  while (i >= d.off[a + 1]) ++a;
  int j = i - d.off[a];
  float v;
  if (*flag) v = ((const float*)d.src[a])[j];
  else       v = b2f(((const bf16*)d.src[a])[j]);
  out[i] = v;
}

// ---------------- CSR build (dst identical for all 4 layers) ----------------

__global__ void count_edges_k(const int* __restrict__ ei, int* __restrict__ counts, int E, int n){
  int e = blockIdx.x * blockDim.x + threadIdx.x;
  if (e >= E + n) return;
  int d = (e < E) ? ei[E + e] : (e - E);   // row 1 of edge_index = dst; tail = self loops
  atomicAdd(&counts[d], 1);
}

__global__ void scan_k(const int* __restrict__ counts, int* __restrict__ row_ptr, int n){
  __shared__ int buf[1024];
  __shared__ int carry_s;
  if (threadIdx.x == 0){ carry_s = 0; row_ptr[0] = 0; }
  __syncthreads();
  for (int base = 0; base < n; base += 1024){
    int i = base + (int)threadIdx.x;
    int v = (i < n) ? counts[i] : 0;
    buf[threadIdx.x] = v;
    __syncthreads();
    for (int off = 1; off < 1024; off <<= 1){
      int t = ((int)threadIdx.x >= off) ? buf[threadIdx.x - off] : 0;
      __syncthreads();
      buf[threadIdx.x] += t;
      __syncthreads();
    }
    if (i < n) row_ptr[i + 1] = carry_s + buf[threadIdx.x];
    __syncthreads();
    if (threadIdx.x == 0) carry_s += buf[1023];
    __syncthreads();
  }
}

__global__ void scatter_k(const int* __restrict__ ei, const int* __restrict__ row_ptr,
                          int* __restrict__ fill, int* __restrict__ esrc, int E, int n){
  int e = blockIdx.x * blockDim.x + threadIdx.x;
  if (e >= E + n) return;
  int s, d;
  if (e < E){ s = ei[e]; d = ei[E + e]; } else { s = e - E; d = s; }
  int pos = row_ptr[d] + atomicAdd(&fill[d], 1);
  esrc[pos] = s;
}

// ---------------- per-layer kernels (all fp32) ----------------

__global__ void linear_k(const float* __restrict__ X, const float* __restrict__ W,
                         float* __restrict__ Y, int n, int din, int dout){
  int idx = blockIdx.x * blockDim.x + threadIdx.x;
  if (idx >= n * dout) return;
  int node = idx / dout;
  int j = idx - node * dout;
  const float* xr = X + (size_t)node * din;
  float acc = 0.f;
  for (int k = 0; k < din; ++k) acc += xr[k] * W[k * dout + j];
  Y[idx] = acc;
}

__global__ void alpha_k(const float* __restrict__ hlin, const float* __restrict__ a_src,
                        const float* __restrict__ a_dst, float* __restrict__ asrc,
                        float* __restrict__ adst, int n, int H, int C){
  int i = blockIdx.x * blockDim.x + threadIdx.x;
  if (i >= n * H) return;
  int node = i / H;
  int head = i - node * H;
  const float* hp = hlin + (size_t)node * (H * C) + head * C;
  float s1 = 0.f, s2 = 0.f;
  for (int c = 0; c < C; ++c){
    float v = hp[c];
    s1 += v * a_src[head * C + c];
    s2 += v * a_dst[head * C + c];
  }
  asrc[i] = s1;
  adst[i] = s2;
}

// Layers 1-3: H=8, C=8 (64 ch). One 64-lane wave per dst node; lane = head*8+j = channel.
__global__ void agg8_k(const float* __restrict__ hlin, const float* __restrict__ asrc,
                       const float* __restrict__ adst, const int* __restrict__ row_ptr,
                       const int* __restrict__ esrc, const float* __restrict__ bias,
                       float* __restrict__ hout, int n){
  int node = (blockIdx.x * blockDim.x + threadIdx.x) >> 6;
  if (node >= n) return;
  int lane = threadIdx.x & 63;
  int head = lane >> 3;
  int j = lane & 7;
  int beg = row_ptr[node], end = row_ptr[node + 1];
  float ad = adst[node * 8 + head];
  float m = -INFINITY;
  for (int p = beg + j; p < end; p += 8){
    int s = esrc[p];
    m = fmaxf(m, lrelu(asrc[s * 8 + head] + ad));
  }
  m = fmaxf(m, __shfl_xor(m, 1));
  m = fmaxf(m, __shfl_xor(m, 2));
  m = fmaxf(m, __shfl_xor(m, 4));
  float acc = 0.f, sw = 0.f;
  for (int p = beg; p < end; ++p){
    int s = esrc[p];
    float w = __expf(lrelu(asrc[s * 8 + head] + ad) - m);
    sw += w;
    acc += hlin[(size_t)s * 64 + lane] * w;
  }
  float o = acc / sw + bias[lane];
  hout[(size_t)node * 64 + lane] = eluf(o);
}

// Layer 4: H=4, C=64, mean over heads. One wave per node; lane = channel.
__global__ void agg4_k(const float* __restrict__ hlin, const float* __restrict__ asrc,
                       const float* __restrict__ adst, const int* __restrict__ row_ptr,
                       const int* __restrict__ esrc, const float* __restrict__ bias,
                       float* __restrict__ hout, int n){
  int node = (blockIdx.x * blockDim.x + threadIdx.x) >> 6;
  if (node >= n) return;
  int lane = threadIdx.x & 63;
  int head = lane >> 4;
  int j = lane & 15;
  int beg = row_ptr[node], end = row_ptr[node + 1];
  float ad_mine = adst[node * 4 + head];
  float m = -INFINITY;
  for (int p = beg + j; p < end; p += 16){
    int s = esrc[p];
    m = fmaxf(m, lrelu(asrc[s * 4 + head] + ad_mine));
  }
  m = fmaxf(m, __shfl_xor(m, 1));
  m = fmaxf(m, __shfl_xor(m, 2));
  m = fmaxf(m, __shfl_xor(m, 4));
  m = fmaxf(m, __shfl_xor(m, 8));
  float mh0 = __shfl(m, 0), mh1 = __shfl(m, 16), mh2 = __shfl(m, 32), mh3 = __shfl(m, 48);
  float ad0 = adst[node * 4 + 0], ad1 = adst[node * 4 + 1];
  float ad2 = adst[node * 4 + 2], ad3 = adst[node * 4 + 3];
  float acc0 = 0.f, acc1 = 0.f, acc2 = 0.f, acc3 = 0.f;
  float sw0 = 0.f, sw1 = 0.f, sw2 = 0.f, sw3 = 0.f;
  for (int p = beg; p < end; ++p){
    int s = esrc[p];
    const float* as = asrc + (size_t)s * 4;
    const float* hr = hlin + (size_t)s * 256;
    float w0 = __expf(lrelu(as[0] + ad0) - mh0); sw0 += w0; acc0 += hr[lane]       * w0;
    float w1 = __expf(lrelu(as[1] + ad1) - mh1); sw1 += w1; acc1 += hr[64 + lane]  * w1;
    float w2 = __expf(lrelu(as[2] + ad2) - mh2); sw2 += w2; acc2 += hr[128 + lane] * w2;
    float w3 = __expf(lrelu(as[3] + ad3) - mh3); sw3 += w3; acc3 += hr[192 + lane] * w3;
  }
  float o = 0.25f * (acc0 / sw0 + acc1 / sw1 + acc2 / sw2 + acc3 / sw3) + bias[lane];
  hout[(size_t)node * 64 + lane] = eluf(o);
}

// ---------------- pooling + head ----------------

__global__ void pool_k(const float* __restrict__ h, const int* __restrict__ fidx,
                       const int* __restrict__ flag_arr, float* __restrict__ fp, int m){
  __shared__ float acc[512];
  for (int t = threadIdx.x; t < 512; t += blockDim.x) acc[t] = 0.f;
  __syncthreads();
  int lane = threadIdx.x & 63;
  int wave = (blockIdx.x * blockDim.x + threadIdx.x) >> 6;
  int nwaves = (gridDim.x * blockDim.x) >> 6;
  for (int i = wave; i < m; i += nwaves){
    int g = flag_arr[i];
    int node = fidx[i];
    atomicAdd(&acc[g * 64 + lane], h[(size_t)node * 64 + lane]);
  }
  __syncthreads();
  for (int t = threadIdx.x; t < 512; t += blockDim.x)
    atomicAdd(&fp[t], acc[t]);
}

__global__ void final_k(const float* __restrict__ fp, const float* __restrict__ h,
                        const int* __restrict__ dec,
                        const float* __restrict__ Wp, const float* __restrict__ Wt,
                        const float* __restrict__ Wo, const float* __restrict__ bo,
                        void* __restrict__ out, const int* __restrict__ dflag){
  int g = threadIdx.x >> 6;
  int j = threadIdx.x & 63;
  const float* fr = fp + g * 64;
  const float* tr = h + (size_t)dec[g] * 64;
  float a = 0.f, b = 0.f;
  for (int k = 0; k < 64; ++k){
    a += fr[k] * Wp[k * 64 + j];
    b += tr[k] * Wt[k * 64 + j];
  }
  float v = eluf(a) * Wo[j] + eluf(b) * Wo[64 + j];
  for (int off = 32; off > 0; off >>= 1) v += __shfl_down(v, off);
  if (j == 0){
    float r = v + bo[0];
    if (*dflag) ((float*)out)[g] = r;
    else        ((bf16*)out)[g] = __float2bfloat16(r);
  }
}

// ---------------- launch ----------------

extern "C" void kernel_launch(void* const* d_in, const int* in_sizes, int n_in,
                              void* d_out, int out_size, void* d_ws, size_t ws_size,
                              hipStream_t stream) {
  const int*  ei    = (const int*)d_in[1];
  const int*  fidx  = (const int*)d_in[2];
  const int*  flagg = (const int*)d_in[3];
  const int*  dec   = (const int*)d_in[4];

  const int N = in_sizes[0] / 16;   // 20000
  const int E = in_sizes[1] / 2;    // 320000
  const int M = in_sizes[2];        // 8000
  const int ET = E + N;

  // float-input arrays (dict order), converted to one fp32 region
  const int fidxs[21] = {0,5,6,7,8,9,10,11,12,13,14,15,16,17,18,19,20,21,22,23,24};
  ConvDesc cd;
  int tot = 0;
  for (int k = 0; k < 21; ++k){
    cd.src[k] = d_in[fidxs[k]];
    cd.off[k] = tot;
    tot += in_sizes[fidxs[k]];
  }
  cd.off[21] = tot;

  // workspace carve
  char* p = (char*)d_ws;
  auto carve = [&](size_t bytes) -> void* {
    void* r = (void*)p;
    p += (bytes + 255) & ~(size_t)255;
    return r;
  };
  int*   dflag   = (int*)carve(4);
  float* conv    = (float*)carve((size_t)tot * 4);
  float* h_lin   = (float*)carve((size_t)N * 256 * 4);
  float* h_agg   = (float*)carve((size_t)N * 64 * 4);
  float* asrc    = (float*)carve((size_t)N * 8 * 4);
  float* adst    = (float*)carve((size_t)N * 8 * 4);
  int*   counts  = (int*)carve((size_t)N * 4);
  int*   row_ptr = (int*)carve((size_t)(N + 1) * 4);
  int*   esrc    = (int*)carve((size_t)ET * 4);
  float* fp      = (float*)carve(8 * 64 * 4);

  if ((size_t)(p - (char*)d_ws) > ws_size) return;  // diagnostic: out stays zero

  const float* cW1 = conv + cd.off[1],  *cas1 = conv + cd.off[2],  *cad1 = conv + cd.off[3],  *cb1 = conv + cd.off[4];
  const float* cW2 = conv + cd.off[5],  *cas2 = conv + cd.off[6],  *cad2 = conv + cd.off[7],  *cb2 = conv + cd.off[8];
  const float* cW3 = conv + cd.off[9],  *cas3 = conv + cd.off[10], *cad3 = conv + cd.off[11], *cb3 = conv + cd.off[12];
  const float* cW4 = conv + cd.off[13], *cas4 = conv + cd.off[14], *cad4 = conv + cd.off[15], *cb4 = conv + cd.off[16];
  const float* cWp = conv + cd.off[17], *cWt = conv + cd.off[18], *cWo = conv + cd.off[19], *cbo = conv + cd.off[20];
  const float* xf  = conv + cd.off[0];

  const int TB = 256;

  // dtype probe + conversion
  hipMemsetAsync(dflag, 0, 4, stream);
  int nprobe = in_sizes[0] < 4096 ? in_sizes[0] : 4096;
  detect_k<<<1, TB, 0, stream>>>((const unsigned short*)d_in[0], nprobe, dflag);
  convert_all_k<<<(tot + TB - 1) / TB, TB, 0, stream>>>(cd, conv, dflag, tot);

  // CSR build
  int eb = (ET + TB - 1) / TB;
  hipMemsetAsync(counts, 0, (size_t)N * 4, stream);
  count_edges_k<<<eb, TB, 0, stream>>>(ei, counts, E, N);
  scan_k<<<1, 1024, 0, stream>>>(counts, row_ptr, N);
  hipMemsetAsync(counts, 0, (size_t)N * 4, stream);
  scatter_k<<<eb, TB, 0, stream>>>(ei, row_ptr, counts, esrc, E, N);

  int agg_blocks = (N * 64 + TB - 1) / TB;

  // layer 1: 16 -> 8x8
  linear_k<<<(N * 64 + TB - 1) / TB, TB, 0, stream>>>(xf, cW1, h_lin, N, 16, 64);
  alpha_k<<<(N * 8 + TB - 1) / TB, TB, 0, stream>>>(h_lin, cas1, cad1, asrc, adst, N, 8, 8);
  agg8_k<<<agg_blocks, TB, 0, stream>>>(h_lin, asrc, adst, row_ptr, esrc, cb1, h_agg, N);

  // layer 2
  linear_k<<<(N * 64 + TB - 1) / TB, TB, 0, stream>>>(h_agg, cW2, h_lin, N, 64, 64);
  alpha_k<<<(N * 8 + TB - 1) / TB, TB, 0, stream>>>(h_lin, cas2, cad2, asrc, adst, N, 8, 8);
  agg8_k<<<agg_blocks, TB, 0, stream>>>(h_lin, asrc, adst, row_ptr, esrc, cb2, h_agg, N);

  // layer 3
  linear_k<<<(N * 64 + TB - 1) / TB, TB, 0, stream>>>(h_agg, cW3, h_lin, N, 64, 64);
  alpha_k<<<(N * 8 + TB - 1) / TB, TB, 0, stream>>>(h_lin, cas3, cad3, asrc, adst, N, 8, 8);
  agg8_k<<<agg_blocks, TB, 0, stream>>>(h_lin, asrc, adst, row_ptr, esrc, cb3, h_agg, N);

  // layer 4: 64 -> 4x64, mean over heads
  linear_k<<<(N * 256 + TB - 1) / TB, TB, 0, stream>>>(h_agg, cW4, h_lin, N, 64, 256);
  alpha_k<<<(N * 4 + TB - 1) / TB, TB, 0, stream>>>(h_lin, cas4, cad4, asrc, adst, N, 4, 64);
  agg4_k<<<agg_blocks, TB, 0, stream>>>(h_lin, asrc, adst, row_ptr, esrc, cb4, h_agg, N);

  // pooling + head
  hipMemsetAsync(fp, 0, 8 * 64 * 4, stream);
  pool_k<<<32, TB, 0, stream>>>(h_agg, fidx, flagg, fp, M);
  final_k<<<1, 512, 0, stream>>>(fp, h_agg, dec, cWp, cWt, cWo, cbo, d_out, dflag);
}

// Round 3
// 540.089 us; speedup vs baseline: 1.2145x; 1.2145x over previous
//
#include <hip/hip_runtime.h>
#include <hip/hip_bf16.h>
#include <math.h>

typedef __hip_bfloat16 bf16;

__device__ __forceinline__ float b2f(bf16 v){ return __bfloat162float(v); }
__device__ __forceinline__ float eluf(float x){ return x > 0.f ? x : __expf(x) - 1.f; }
__device__ __forceinline__ float lrelu(float x){ return x > 0.f ? x : 0.2f * x; }

// ---------------- dtype detection ----------------
// flag: 0 = bf16 inputs, 1 = fp32 inputs. (Round-2 evidence: bf16. Probe kept
// for robustness; costs ~2 us.)
__global__ void detect_k(const unsigned short* __restrict__ u16, int n, int* __restrict__ flag){
  int bad = 0;
  for (int k = threadIdx.x; k < n; k += 256){
    int ex = (u16[k] >> 7) & 0xFF;
    if (ex >= 0xC6) bad = 1;
  }
  if (__any(bad) && (threadIdx.x & 63) == 0) atomicOr(flag, 1);
}

// ---------------- unified input conversion to fp32 ----------------
struct ConvDesc {
  const void* src[21];
  int off[22];
};

__global__ void convert_all_k(ConvDesc d, float* __restrict__ out,
                              const int* __restrict__ flag, int total){
  int i = blockIdx.x * blockDim.x + threadIdx.x;
  if (i >= total) return;
  int a = 0;
  while (i >= d.off[a + 1]) ++a;
  int j = i - d.off[a];
  float v;
  if (*flag) v = ((const float*)d.src[a])[j];
  else       v = b2f(((const bf16*)d.src[a])[j]);
  out[i] = v;
}

// ---------------- CSR build (dst identical for all 4 layers) ----------------

__global__ void count_edges_k(const int* __restrict__ ei, int* __restrict__ counts, int E, int n){
  int e = blockIdx.x * blockDim.x + threadIdx.x;
  if (e >= E + n) return;
  int d = (e < E) ? ei[E + e] : (e - E);
  atomicAdd(&counts[d], 1);
}

// serial-per-thread chunks + one 1024-wide Hillis-Steele (was 20x slower tiled scan)
__global__ void scan_k(const int* __restrict__ counts, int* __restrict__ row_ptr, int n){
  __shared__ int psum[1024];
  int t = threadIdx.x;
  int chunk = (n + 1023) >> 10;
  int beg = t * chunk;
  int end = beg + chunk; if (end > n) end = n;
  int s = 0;
  for (int i = beg; i < end; ++i) s += counts[i];
  psum[t] = s;
  __syncthreads();
  for (int off = 1; off < 1024; off <<= 1){
    int v = (t >= off) ? psum[t - off] : 0;
    __syncthreads();
    psum[t] += v;
    __syncthreads();
  }
  int run = psum[t] - s;  // exclusive prefix of this chunk
  for (int i = beg; i < end; ++i){ row_ptr[i] = run; run += counts[i]; }
  if (beg < n && end == n) row_ptr[n] = run;
}

__global__ void scatter_k(const int* __restrict__ ei, const int* __restrict__ row_ptr,
                          int* __restrict__ fill, int* __restrict__ esrc, int E, int n){
  int e = blockIdx.x * blockDim.x + threadIdx.x;
  if (e >= E + n) return;
  int s, d;
  if (e < E){ s = ei[e]; d = ei[E + e]; } else { s = e - E; d = s; }
  int pos = row_ptr[d] + atomicAdd(&fill[d], 1);
  esrc[pos] = s;
}

// ---------------- tiled linear: Y[n,M] = X[n,K] @ W[K,M] ----------------
// Block = 256 threads, 64-node tile. X tile staged TRANSPOSED in LDS (pad 65)
// so inner-loop reads are broadcast/conflict-free. Lane owns an output quad:
// W float4 loads and Y float4 stores are fully coalesced (1KB/wave).
template<int K, int M>
__global__ void linear_t_k(const float* __restrict__ X, const float* __restrict__ W,
                           float* __restrict__ Y, int n){
  constexpr int MQ  = M / 4;       // output quads per row
  constexpr int NPW = 64 / MQ;     // nodes per wave-iteration (4 for M=64, 1 for M=256)
  constexpr int ITERS = 64 / (4 * NPW);
  __shared__ float xt[K][65];
  int base = blockIdx.x * 64;
  int t = threadIdx.x;
  // cooperative transpose-stage: 64*K floats as float4
  for (int q = t; q < 64 * (K / 4); q += 256){
    int node = q / (K / 4);
    int k4 = q - node * (K / 4);
    float4 v = make_float4(0.f, 0.f, 0.f, 0.f);
    if (base + node < n) v = ((const float4*)(X + (size_t)(base + node) * K))[k4];
    xt[k4 * 4 + 0][node] = v.x;
    xt[k4 * 4 + 1][node] = v.y;
    xt[k4 * 4 + 2][node] = v.z;
    xt[k4 * 4 + 3][node] = v.w;
  }
  __syncthreads();
  int lane = t & 63, wv = t >> 6;
  int jj = lane % MQ;       // output quad owned by this lane
  int no = lane / MQ;       // node offset within wave-iteration
#pragma unroll
  for (int it = 0; it < ITERS; ++it){
    int nl = (it * 4 + wv) * NPW + no;
    float ax = 0.f, ay = 0.f, az = 0.f, aw = 0.f;
#pragma unroll 8
    for (int k = 0; k < K; ++k){
      float xv = xt[k][nl];
      float4 w = ((const float4*)(W + (size_t)k * M))[jj];
      ax += xv * w.x; ay += xv * w.y; az += xv * w.z; aw += xv * w.w;
    }
    int node = base + nl;
    if (node < n){
      float4 o = make_float4(ax, ay, az, aw);
      ((float4*)(Y + (size_t)node * M))[jj] = o;
    }
  }
}

// asrc[n*H+h] = dot(h[n,h,:], a_src[h,:]); float4 loads.
__global__ void alpha_k(const float* __restrict__ hlin, const float* __restrict__ a_src,
                        const float* __restrict__ a_dst, float* __restrict__ asrc,
                        float* __restrict__ adst, int n, int H, int C){
  int i = blockIdx.x * blockDim.x + threadIdx.x;
  if (i >= n * H) return;
  int node = i / H;
  int head = i - node * H;
  const float4* hp  = (const float4*)(hlin + (size_t)node * H * C + head * C);
  const float4* asp = (const float4*)(a_src + head * C);
  const float4* adp = (const float4*)(a_dst + head * C);
  float s1 = 0.f, s2 = 0.f;
  for (int c = 0; c < C / 4; ++c){
    float4 v = hp[c], a = asp[c], d = adp[c];
    s1 += v.x * a.x + v.y * a.y + v.z * a.z + v.w * a.w;
    s2 += v.x * d.x + v.y * d.y + v.z * d.z + v.w * d.w;
  }
  asrc[i] = s1;
  adst[i] = s2;
}

// Layers 1-3: H=8, C=8. One wave per dst node; lane = head*8+j = channel.
__global__ void agg8_k(const float* __restrict__ hlin, const float* __restrict__ asrc,
                       const float* __restrict__ adst, const int* __restrict__ row_ptr,
                       const int* __restrict__ esrc, const float* __restrict__ bias,
                       float* __restrict__ hout, int n){
  int node = (blockIdx.x * blockDim.x + threadIdx.x) >> 6;
  if (node >= n) return;
  int lane = threadIdx.x & 63;
  int head = lane >> 3;
  int j = lane & 7;
  int beg = row_ptr[node], end = row_ptr[node + 1];
  float ad = adst[node * 8 + head];
  float m = -INFINITY;
  for (int p = beg + j; p < end; p += 8){
    int s = esrc[p];
    m = fmaxf(m, lrelu(asrc[s * 8 + head] + ad));
  }
  m = fmaxf(m, __shfl_xor(m, 1));
  m = fmaxf(m, __shfl_xor(m, 2));
  m = fmaxf(m, __shfl_xor(m, 4));
  float acc = 0.f, sw = 0.f;
  for (int p = beg; p < end; ++p){
    int s = esrc[p];
    float w = __expf(lrelu(asrc[s * 8 + head] + ad) - m);
    sw += w;
    acc += hlin[(size_t)s * 64 + lane] * w;
  }
  float o = acc / sw + bias[lane];
  hout[(size_t)node * 64 + lane] = eluf(o);
}

// Layer 4: H=4, C=64, mean over heads. One wave per node; lane = channel.
__global__ void agg4_k(const float* __restrict__ hlin, const float* __restrict__ asrc,
                       const float* __restrict__ adst, const int* __restrict__ row_ptr,
                       const int* __restrict__ esrc, const float* __restrict__ bias,
                       float* __restrict__ hout, int n){
  int node = (blockIdx.x * blockDim.x + threadIdx.x) >> 6;
  if (node >= n) return;
  int lane = threadIdx.x & 63;
  int head = lane >> 4;
  int j = lane & 15;
  int beg = row_ptr[node], end = row_ptr[node + 1];
  float ad_mine = adst[node * 4 + head];
  float m = -INFINITY;
  for (int p = beg + j; p < end; p += 16){
    int s = esrc[p];
    m = fmaxf(m, lrelu(asrc[s * 4 + head] + ad_mine));
  }
  m = fmaxf(m, __shfl_xor(m, 1));
  m = fmaxf(m, __shfl_xor(m, 2));
  m = fmaxf(m, __shfl_xor(m, 4));
  m = fmaxf(m, __shfl_xor(m, 8));
  float mh0 = __shfl(m, 0), mh1 = __shfl(m, 16), mh2 = __shfl(m, 32), mh3 = __shfl(m, 48);
  float ad0 = adst[node * 4 + 0], ad1 = adst[node * 4 + 1];
  float ad2 = adst[node * 4 + 2], ad3 = adst[node * 4 + 3];
  float acc0 = 0.f, acc1 = 0.f, acc2 = 0.f, acc3 = 0.f;
  float sw0 = 0.f, sw1 = 0.f, sw2 = 0.f, sw3 = 0.f;
  for (int p = beg; p < end; ++p){
    int s = esrc[p];
    const float* as = asrc + (size_t)s * 4;
    const float* hr = hlin + (size_t)s * 256;
    float w0 = __expf(lrelu(as[0] + ad0) - mh0); sw0 += w0; acc0 += hr[lane]       * w0;
    float w1 = __expf(lrelu(as[1] + ad1) - mh1); sw1 += w1; acc1 += hr[64 + lane]  * w1;
    float w2 = __expf(lrelu(as[2] + ad2) - mh2); sw2 += w2; acc2 += hr[128 + lane] * w2;
    float w3 = __expf(lrelu(as[3] + ad3) - mh3); sw3 += w3; acc3 += hr[192 + lane] * w3;
  }
  float o = 0.25f * (acc0 / sw0 + acc1 / sw1 + acc2 / sw2 + acc3 / sw3) + bias[lane];
  hout[(size_t)node * 64 + lane] = eluf(o);
}

// ---------------- pooling + head ----------------

__global__ void pool_k(const float* __restrict__ h, const int* __restrict__ fidx,
                       const int* __restrict__ flag_arr, float* __restrict__ fp, int m){
  __shared__ float acc[512];
  for (int t = threadIdx.x; t < 512; t += blockDim.x) acc[t] = 0.f;
  __syncthreads();
  int lane = threadIdx.x & 63;
  int wave = (blockIdx.x * blockDim.x + threadIdx.x) >> 6;
  int nwaves = (gridDim.x * blockDim.x) >> 6;
  for (int i = wave; i < m; i += nwaves){
    int g = flag_arr[i];
    int node = fidx[i];
    atomicAdd(&acc[g * 64 + lane], h[(size_t)node * 64 + lane]);
  }
  __syncthreads();
  for (int t = threadIdx.x; t < 512; t += blockDim.x)
    atomicAdd(&fp[t], acc[t]);
}

__global__ void final_k(const float* __restrict__ fp, const float* __restrict__ h,
                        const int* __restrict__ dec,
                        const float* __restrict__ Wp, const float* __restrict__ Wt,
                        const float* __restrict__ Wo, const float* __restrict__ bo,
                        void* __restrict__ out, const int* __restrict__ dflag){
  int g = threadIdx.x >> 6;
  int j = threadIdx.x & 63;
  const float* fr = fp + g * 64;
  const float* tr = h + (size_t)dec[g] * 64;
  float a = 0.f, b = 0.f;
  for (int k = 0; k < 64; ++k){
    a += fr[k] * Wp[k * 64 + j];
    b += tr[k] * Wt[k * 64 + j];
  }
  float v = eluf(a) * Wo[j] + eluf(b) * Wo[64 + j];
  for (int off = 32; off > 0; off >>= 1) v += __shfl_down(v, off);
  if (j == 0){
    float r = v + bo[0];
    if (*dflag) ((float*)out)[g] = r;
    else        ((bf16*)out)[g] = __float2bfloat16(r);
  }
}

// ---------------- launch ----------------

extern "C" void kernel_launch(void* const* d_in, const int* in_sizes, int n_in,
                              void* d_out, int out_size, void* d_ws, size_t ws_size,
                              hipStream_t stream) {
  const int*  ei    = (const int*)d_in[1];
  const int*  fidx  = (const int*)d_in[2];
  const int*  flagg = (const int*)d_in[3];
  const int*  dec   = (const int*)d_in[4];

  const int N = in_sizes[0] / 16;   // 20000
  const int E = in_sizes[1] / 2;    // 320000
  const int M = in_sizes[2];        // 8000
  const int ET = E + N;

  const int fidxs[21] = {0,5,6,7,8,9,10,11,12,13,14,15,16,17,18,19,20,21,22,23,24};
  ConvDesc cd;
  int tot = 0;
  for (int k = 0; k < 21; ++k){
    cd.src[k] = d_in[fidxs[k]];
    cd.off[k] = tot;
    tot += in_sizes[fidxs[k]];
  }
  cd.off[21] = tot;

  char* p = (char*)d_ws;
  auto carve = [&](size_t bytes) -> void* {
    void* r = (void*)p;
    p += (bytes + 255) & ~(size_t)255;
    return r;
  };
  int*   dflag   = (int*)carve(4);
  float* conv    = (float*)carve((size_t)tot * 4);
  float* h_lin   = (float*)carve((size_t)N * 256 * 4);
  float* h_agg   = (float*)carve((size_t)N * 64 * 4);
  float* asrc    = (float*)carve((size_t)N * 8 * 4);
  float* adst    = (float*)carve((size_t)N * 8 * 4);
  int*   counts  = (int*)carve((size_t)N * 4);
  int*   row_ptr = (int*)carve((size_t)(N + 1) * 4);
  int*   esrc    = (int*)carve((size_t)ET * 4);
  float* fp      = (float*)carve(8 * 64 * 4);

  if ((size_t)(p - (char*)d_ws) > ws_size) return;

  const float* cW1 = conv + cd.off[1],  *cas1 = conv + cd.off[2],  *cad1 = conv + cd.off[3],  *cb1 = conv + cd.off[4];
  const float* cW2 = conv + cd.off[5],  *cas2 = conv + cd.off[6],  *cad2 = conv + cd.off[7],  *cb2 = conv + cd.off[8];
  const float* cW3 = conv + cd.off[9],  *cas3 = conv + cd.off[10], *cad3 = conv + cd.off[11], *cb3 = conv + cd.off[12];
  const float* cW4 = conv + cd.off[13], *cas4 = conv + cd.off[14], *cad4 = conv + cd.off[15], *cb4 = conv + cd.off[16];
  const float* cWp = conv + cd.off[17], *cWt = conv + cd.off[18], *cWo = conv + cd.off[19], *cbo = conv + cd.off[20];
  const float* xf  = conv + cd.off[0];

  const int TB = 256;

  hipMemsetAsync(dflag, 0, 4, stream);
  int nprobe = in_sizes[0] < 4096 ? in_sizes[0] : 4096;
  detect_k<<<1, TB, 0, stream>>>((const unsigned short*)d_in[0], nprobe, dflag);
  convert_all_k<<<(tot + TB - 1) / TB, TB, 0, stream>>>(cd, conv, dflag, tot);

  int eb = (ET + TB - 1) / TB;
  hipMemsetAsync(counts, 0, (size_t)N * 4, stream);
  count_edges_k<<<eb, TB, 0, stream>>>(ei, counts, E, N);
  scan_k<<<1, 1024, 0, stream>>>(counts, row_ptr, N);
  hipMemsetAsync(counts, 0, (size_t)N * 4, stream);
  scatter_k<<<eb, TB, 0, stream>>>(ei, row_ptr, counts, esrc, E, N);

  int agg_blocks = (N * 64 + TB - 1) / TB;
  int lin_blocks = (N + 63) / 64;

  // layer 1: 16 -> 8x8
  linear_t_k<16, 64><<<lin_blocks, TB, 0, stream>>>(xf, cW1, h_lin, N);
  alpha_k<<<(N * 8 + TB - 1) / TB, TB, 0, stream>>>(h_lin, cas1, cad1, asrc, adst, N, 8, 8);
  agg8_k<<<agg_blocks, TB, 0, stream>>>(h_lin, asrc, adst, row_ptr, esrc, cb1, h_agg, N);

  // layer 2
  linear_t_k<64, 64><<<lin_blocks, TB, 0, stream>>>(h_agg, cW2, h_lin, N);
  alpha_k<<<(N * 8 + TB - 1) / TB, TB, 0, stream>>>(h_lin, cas2, cad2, asrc, adst, N, 8, 8);
  agg8_k<<<agg_blocks, TB, 0, stream>>>(h_lin, asrc, adst, row_ptr, esrc, cb2, h_agg, N);

  // layer 3
  linear_t_k<64, 64><<<lin_blocks, TB, 0, stream>>>(h_agg, cW3, h_lin, N);
  alpha_k<<<(N * 8 + TB - 1) / TB, TB, 0, stream>>>(h_lin, cas3, cad3, asrc, adst, N, 8, 8);
  agg8_k<<<agg_blocks, TB, 0, stream>>>(h_lin, asrc, adst, row_ptr, esrc, cb3, h_agg, N);

  // layer 4: 64 -> 4x64, mean over heads
  linear_t_k<64, 256><<<lin_blocks, TB, 0, stream>>>(h_agg, cW4, h_lin, N);
  alpha_k<<<(N * 4 + TB - 1) / TB, TB, 0, stream>>>(h_lin, cas4, cad4, asrc, adst, N, 4, 64);
  agg4_k<<<agg_blocks, TB, 0, stream>>>(h_lin, asrc, adst, row_ptr, esrc, cb4, h_agg, N);

  hipMemsetAsync(fp, 0, 8 * 64 * 4, stream);
  pool_k<<<32, TB, 0, stream>>>(h_agg, fidx, flagg, fp, M);
  final_k<<<1, 512, 0, stream>>>(fp, h_agg, dec, cWp, cWt, cWo, cbo, d_out, dflag);
}

// Round 4
// 488.615 us; speedup vs baseline: 1.3424x; 1.1053x over previous
//
#include <hip/hip_runtime.h>
#include <hip/hip_bf16.h>
#include <math.h>

typedef __hip_bfloat16 bf16;

__device__ __forceinline__ float b2f(bf16 v){ return __bfloat162float(v); }
__device__ __forceinline__ float eluf(float x){ return x > 0.f ? x : __expf(x) - 1.f; }
__device__ __forceinline__ float lrelu(float x){ return x > 0.f ? x : 0.2f * x; }

// ---------------- dtype detection ----------------
// flag: 0 = bf16 inputs, 1 = fp32 inputs. (Round-2 evidence: bf16.)
__global__ void detect_k(const unsigned short* __restrict__ u16, int n, int* __restrict__ flag){
  int bad = 0;
  for (int k = threadIdx.x; k < n; k += 256){
    int ex = (u16[k] >> 7) & 0xFF;
    if (ex >= 0xC6) bad = 1;
  }
  if (__any(bad) && (threadIdx.x & 63) == 0) atomicOr(flag, 1);
}

// ---------------- unified input conversion to fp32 ----------------
struct ConvDesc {
  const void* src[21];
  int off[22];
};

__global__ void convert_all_k(ConvDesc d, float* __restrict__ out,
                              const int* __restrict__ flag, int total){
  int i = blockIdx.x * blockDim.x + threadIdx.x;
  if (i >= total) return;
  int a = 0;
  while (i >= d.off[a + 1]) ++a;
  int j = i - d.off[a];
  float v;
  if (*flag) v = ((const float*)d.src[a])[j];
  else       v = b2f(((const bf16*)d.src[a])[j]);
  out[i] = v;
}

// ---------------- CSR build (dst identical for all 4 layers) ----------------

__global__ void count_edges_k(const int* __restrict__ ei, int* __restrict__ counts, int E, int n){
  int e = blockIdx.x * blockDim.x + threadIdx.x;
  if (e >= E + n) return;
  int d = (e < E) ? ei[E + e] : (e - E);
  atomicAdd(&counts[d], 1);
}

__global__ void scan_k(const int* __restrict__ counts, int* __restrict__ row_ptr, int n){
  __shared__ int psum[1024];
  int t = threadIdx.x;
  int chunk = (n + 1023) >> 10;
  int beg = t * chunk;
  int end = beg + chunk; if (end > n) end = n;
  int s = 0;
  for (int i = beg; i < end; ++i) s += counts[i];
  psum[t] = s;
  __syncthreads();
  for (int off = 1; off < 1024; off <<= 1){
    int v = (t >= off) ? psum[t - off] : 0;
    __syncthreads();
    psum[t] += v;
    __syncthreads();
  }
  int run = psum[t] - s;
  for (int i = beg; i < end; ++i){ row_ptr[i] = run; run += counts[i]; }
  if (beg < n && end == n) row_ptr[n] = run;
}

__global__ void scatter_k(const int* __restrict__ ei, const int* __restrict__ row_ptr,
                          int* __restrict__ fill, int* __restrict__ esrc, int E, int n){
  int e = blockIdx.x * blockDim.x + threadIdx.x;
  if (e >= E + n) return;
  int s, d;
  if (e < E){ s = ei[e]; d = ei[E + e]; } else { s = e - E; d = s; }
  int pos = row_ptr[d] + atomicAdd(&fill[d], 1);
  esrc[pos] = s;
}

// ---------------- tiled linear with W in LDS ----------------
// Y[n, mb0:mb0+MB] = X[n,K] @ W[K, mb0:mb0+MB].  Block = 256 thr, 64-node tile,
// blockIdx.y selects the MB-wide channel slice.  W slice AND transposed X tile
// both staged in LDS; the K-loop has ZERO global memory ops (was: full-W L2
// restream per node => 1.3 GB L2 traffic; now 20 MB).
template<int K, int M, int MB>
__global__ void linear_w_k(const float* __restrict__ X, const float* __restrict__ W,
                           float* __restrict__ Y, int n){
  constexpr int MQ  = MB / 4;        // float4 quads per node-slice
  constexpr int NPW = 64 / MQ;       // nodes per wave-iteration
  constexpr int ITERS = 64 / (4 * NPW);
  __shared__ float wl[K * MB];
  __shared__ float xt[K][65];
  int base = blockIdx.x * 64;
  int mb0  = blockIdx.y * MB;
  int t = threadIdx.x;
  // stage W slice (coalesced float4)
  for (int q = t; q < K * MQ; q += 256){
    int k = q / MQ, j = q - k * MQ;
    ((float4*)wl)[q] = ((const float4*)(W + (size_t)k * M + mb0))[j];
  }
  // stage X transposed
  for (int q = t; q < 64 * (K / 4); q += 256){
    int node = q / (K / 4);
    int k4 = q - node * (K / 4);
    float4 v = make_float4(0.f, 0.f, 0.f, 0.f);
    if (base + node < n) v = ((const float4*)(X + (size_t)(base + node) * K))[k4];
    xt[k4 * 4 + 0][node] = v.x;
    xt[k4 * 4 + 1][node] = v.y;
    xt[k4 * 4 + 2][node] = v.z;
    xt[k4 * 4 + 3][node] = v.w;
  }
  __syncthreads();
  int lane = t & 63, wv = t >> 6;
  int jj = lane % MQ;
  int no = lane / MQ;
#pragma unroll
  for (int it = 0; it < ITERS; ++it){
    int nl = (it * 4 + wv) * NPW + no;
    float ax = 0.f, ay = 0.f, az = 0.f, aw = 0.f;
#pragma unroll 8
    for (int k = 0; k < K; ++k){
      float xv = xt[k][nl];
      float4 w = ((const float4*)wl)[k * MQ + jj];
      ax += xv * w.x; ay += xv * w.y; az += xv * w.z; aw += xv * w.w;
    }
    int node = base + nl;
    if (node < n)
      ((float4*)(Y + (size_t)node * M + mb0))[jj] = make_float4(ax, ay, az, aw);
  }
}

// asrc[n*H+h] = dot(h[n,h,:], a_src[h,:]); float4 loads.
__global__ void alpha_k(const float* __restrict__ hlin, const float* __restrict__ a_src,
                        const float* __restrict__ a_dst, float* __restrict__ asrc,
                        float* __restrict__ adst, int n, int H, int C){
  int i = blockIdx.x * blockDim.x + threadIdx.x;
  if (i >= n * H) return;
  int node = i / H;
  int head = i - node * H;
  const float4* hp  = (const float4*)(hlin + (size_t)node * H * C + head * C);
  const float4* asp = (const float4*)(a_src + head * C);
  const float4* adp = (const float4*)(a_dst + head * C);
  float s1 = 0.f, s2 = 0.f;
  for (int c = 0; c < C / 4; ++c){
    float4 v = hp[c], a = asp[c], d = adp[c];
    s1 += v.x * a.x + v.y * a.y + v.z * a.z + v.w * a.w;
    s2 += v.x * d.x + v.y * d.y + v.z * d.z + v.w * d.w;
  }
  asrc[i] = s1;
  adst[i] = s2;
}

// Layers 1-3: H=8, C=8. One wave per dst node; lane = head*8+j = channel.
__global__ void agg8_k(const float* __restrict__ hlin, const float* __restrict__ asrc,
                       const float* __restrict__ adst, const int* __restrict__ row_ptr,
                       const int* __restrict__ esrc, const float* __restrict__ bias,
                       float* __restrict__ hout, int n){
  int node = (blockIdx.x * blockDim.x + threadIdx.x) >> 6;
  if (node >= n) return;
  int lane = threadIdx.x & 63;
  int head = lane >> 3;
  int j = lane & 7;
  int beg = row_ptr[node], end = row_ptr[node + 1];
  float ad = adst[node * 8 + head];
  float m = -INFINITY;
  for (int p = beg + j; p < end; p += 8){
    int s = esrc[p];
    m = fmaxf(m, lrelu(asrc[s * 8 + head] + ad));
  }
  m = fmaxf(m, __shfl_xor(m, 1));
  m = fmaxf(m, __shfl_xor(m, 2));
  m = fmaxf(m, __shfl_xor(m, 4));
  float acc = 0.f, sw = 0.f;
  for (int p = beg; p < end; ++p){
    int s = esrc[p];
    float w = __expf(lrelu(asrc[s * 8 + head] + ad) - m);
    sw += w;
    acc += hlin[(size_t)s * 64 + lane] * w;
  }
  float o = acc / sw + bias[lane];
  hout[(size_t)node * 64 + lane] = eluf(o);
}

// Layer 4: H=4, C=64, mean over heads. One wave per node; lane = channel.
__global__ void agg4_k(const float* __restrict__ hlin, const float* __restrict__ asrc,
                       const float* __restrict__ adst, const int* __restrict__ row_ptr,
                       const int* __restrict__ esrc, const float* __restrict__ bias,
                       float* __restrict__ hout, int n){
  int node = (blockIdx.x * blockDim.x + threadIdx.x) >> 6;
  if (node >= n) return;
  int lane = threadIdx.x & 63;
  int head = lane >> 4;
  int j = lane & 15;
  int beg = row_ptr[node], end = row_ptr[node + 1];
  float ad_mine = adst[node * 4 + head];
  float m = -INFINITY;
  for (int p = beg + j; p < end; p += 16){
    int s = esrc[p];
    m = fmaxf(m, lrelu(asrc[s * 4 + head] + ad_mine));
  }
  m = fmaxf(m, __shfl_xor(m, 1));
  m = fmaxf(m, __shfl_xor(m, 2));
  m = fmaxf(m, __shfl_xor(m, 4));
  m = fmaxf(m, __shfl_xor(m, 8));
  float mh0 = __shfl(m, 0), mh1 = __shfl(m, 16), mh2 = __shfl(m, 32), mh3 = __shfl(m, 48);
  float ad0 = adst[node * 4 + 0], ad1 = adst[node * 4 + 1];
  float ad2 = adst[node * 4 + 2], ad3 = adst[node * 4 + 3];
  float acc0 = 0.f, acc1 = 0.f, acc2 = 0.f, acc3 = 0.f;
  float sw0 = 0.f, sw1 = 0.f, sw2 = 0.f, sw3 = 0.f;
  for (int p = beg; p < end; ++p){
    int s = esrc[p];
    const float* as = asrc + (size_t)s * 4;
    const float* hr = hlin + (size_t)s * 256;
    float w0 = __expf(lrelu(as[0] + ad0) - mh0); sw0 += w0; acc0 += hr[lane]       * w0;
    float w1 = __expf(lrelu(as[1] + ad1) - mh1); sw1 += w1; acc1 += hr[64 + lane]  * w1;
    float w2 = __expf(lrelu(as[2] + ad2) - mh2); sw2 += w2; acc2 += hr[128 + lane] * w2;
    float w3 = __expf(lrelu(as[3] + ad3) - mh3); sw3 += w3; acc3 += hr[192 + lane] * w3;
  }
  float o = 0.25f * (acc0 / sw0 + acc1 / sw1 + acc2 / sw2 + acc3 / sw3) + bias[lane];
  hout[(size_t)node * 64 + lane] = eluf(o);
}

// ---------------- pooling + head ----------------

__global__ void pool_k(const float* __restrict__ h, const int* __restrict__ fidx,
                       const int* __restrict__ flag_arr, float* __restrict__ fp, int m){
  __shared__ float acc[512];
  for (int t = threadIdx.x; t < 512; t += blockDim.x) acc[t] = 0.f;
  __syncthreads();
  int lane = threadIdx.x & 63;
  int wave = (blockIdx.x * blockDim.x + threadIdx.x) >> 6;
  int nwaves = (gridDim.x * blockDim.x) >> 6;
  for (int i = wave; i < m; i += nwaves){
    int g = flag_arr[i];
    int node = fidx[i];
    atomicAdd(&acc[g * 64 + lane], h[(size_t)node * 64 + lane]);
  }
  __syncthreads();
  for (int t = threadIdx.x; t < 512; t += blockDim.x)
    atomicAdd(&fp[t], acc[t]);
}

__global__ void final_k(const float* __restrict__ fp, const float* __restrict__ h,
                        const int* __restrict__ dec,
                        const float* __restrict__ Wp, const float* __restrict__ Wt,
                        const float* __restrict__ Wo, const float* __restrict__ bo,
                        void* __restrict__ out, const int* __restrict__ dflag){
  int g = threadIdx.x >> 6;
  int j = threadIdx.x & 63;
  const float* fr = fp + g * 64;
  const float* tr = h + (size_t)dec[g] * 64;
  float a = 0.f, b = 0.f;
  for (int k = 0; k < 64; ++k){
    a += fr[k] * Wp[k * 64 + j];
    b += tr[k] * Wt[k * 64 + j];
  }
  float v = eluf(a) * Wo[j] + eluf(b) * Wo[64 + j];
  for (int off = 32; off > 0; off >>= 1) v += __shfl_down(v, off);
  if (j == 0){
    float r = v + bo[0];
    if (*dflag) ((float*)out)[g] = r;
    else        ((bf16*)out)[g] = __float2bfloat16(r);
  }
}

// ---------------- launch ----------------

extern "C" void kernel_launch(void* const* d_in, const int* in_sizes, int n_in,
                              void* d_out, int out_size, void* d_ws, size_t ws_size,
                              hipStream_t stream) {
  const int*  ei    = (const int*)d_in[1];
  const int*  fidx  = (const int*)d_in[2];
  const int*  flagg = (const int*)d_in[3];
  const int*  dec   = (const int*)d_in[4];

  const int N = in_sizes[0] / 16;   // 20000
  const int E = in_sizes[1] / 2;    // 320000
  const int M = in_sizes[2];        // 8000
  const int ET = E + N;

  const int fidxs[21] = {0,5,6,7,8,9,10,11,12,13,14,15,16,17,18,19,20,21,22,23,24};
  ConvDesc cd;
  int tot = 0;
  for (int k = 0; k < 21; ++k){
    cd.src[k] = d_in[fidxs[k]];
    cd.off[k] = tot;
    tot += in_sizes[fidxs[k]];
  }
  cd.off[21] = tot;

  char* p = (char*)d_ws;
  auto carve = [&](size_t bytes) -> void* {
    void* r = (void*)p;
    p += (bytes + 255) & ~(size_t)255;
    return r;
  };
  int*   dflag   = (int*)carve(4);
  float* conv    = (float*)carve((size_t)tot * 4);
  float* h_lin   = (float*)carve((size_t)N * 256 * 4);
  float* h_agg   = (float*)carve((size_t)N * 64 * 4);
  float* asrc    = (float*)carve((size_t)N * 8 * 4);
  float* adst    = (float*)carve((size_t)N * 8 * 4);
  int*   counts  = (int*)carve((size_t)N * 4);
  int*   row_ptr = (int*)carve((size_t)(N + 1) * 4);
  int*   esrc    = (int*)carve((size_t)ET * 4);
  float* fp      = (float*)carve(8 * 64 * 4);

  if ((size_t)(p - (char*)d_ws) > ws_size) return;

  const float* cW1 = conv + cd.off[1],  *cas1 = conv + cd.off[2],  *cad1 = conv + cd.off[3],  *cb1 = conv + cd.off[4];
  const float* cW2 = conv + cd.off[5],  *cas2 = conv + cd.off[6],  *cad2 = conv + cd.off[7],  *cb2 = conv + cd.off[8];
  const float* cW3 = conv + cd.off[9],  *cas3 = conv + cd.off[10], *cad3 = conv + cd.off[11], *cb3 = conv + cd.off[12];
  const float* cW4 = conv + cd.off[13], *cas4 = conv + cd.off[14], *cad4 = conv + cd.off[15], *cb4 = conv + cd.off[16];
  const float* cWp = conv + cd.off[17], *cWt = conv + cd.off[18], *cWo = conv + cd.off[19], *cbo = conv + cd.off[20];
  const float* xf  = conv + cd.off[0];

  const int TB = 256;

  hipMemsetAsync(dflag, 0, 4, stream);
  int nprobe = in_sizes[0] < 4096 ? in_sizes[0] : 4096;
  detect_k<<<1, TB, 0, stream>>>((const unsigned short*)d_in[0], nprobe, dflag);
  convert_all_k<<<(tot + TB - 1) / TB, TB, 0, stream>>>(cd, conv, dflag, tot);

  int eb = (ET + TB - 1) / TB;
  hipMemsetAsync(counts, 0, (size_t)N * 4, stream);
  count_edges_k<<<eb, TB, 0, stream>>>(ei, counts, E, N);
  scan_k<<<1, 1024, 0, stream>>>(counts, row_ptr, N);
  hipMemsetAsync(counts, 0, (size_t)N * 4, stream);
  scatter_k<<<eb, TB, 0, stream>>>(ei, row_ptr, counts, esrc, E, N);

  int agg_blocks = (N * 64 + TB - 1) / TB;
  int lin_blocks = (N + 63) / 64;

  // layer 1: 16 -> 8x8
  linear_w_k<16, 64, 64><<<dim3(lin_blocks, 1), TB, 0, stream>>>(xf, cW1, h_lin, N);
  alpha_k<<<(N * 8 + TB - 1) / TB, TB, 0, stream>>>(h_lin, cas1, cad1, asrc, adst, N, 8, 8);
  agg8_k<<<agg_blocks, TB, 0, stream>>>(h_lin, asrc, adst, row_ptr, esrc, cb1, h_agg, N);

  // layer 2
  linear_w_k<64, 64, 64><<<dim3(lin_blocks, 1), TB, 0, stream>>>(h_agg, cW2, h_lin, N);
  alpha_k<<<(N * 8 + TB - 1) / TB, TB, 0, stream>>>(h_lin, cas2, cad2, asrc, adst, N, 8, 8);
  agg8_k<<<agg_blocks, TB, 0, stream>>>(h_lin, asrc, adst, row_ptr, esrc, cb2, h_agg, N);

  // layer 3
  linear_w_k<64, 64, 64><<<dim3(lin_blocks, 1), TB, 0, stream>>>(h_agg, cW3, h_lin, N);
  alpha_k<<<(N * 8 + TB - 1) / TB, TB, 0, stream>>>(h_lin, cas3, cad3, asrc, adst, N, 8, 8);
  agg8_k<<<agg_blocks, TB, 0, stream>>>(h_lin, asrc, adst, row_ptr, esrc, cb3, h_agg, N);

  // layer 4: 64 -> 4x64, mean over heads; channel slice split over blockIdx.y
  linear_w_k<64, 256, 128><<<dim3(lin_blocks, 2), TB, 0, stream>>>(h_agg, cW4, h_lin, N);
  alpha_k<<<(N * 4 + TB - 1) / TB, TB, 0, stream>>>(h_lin, cas4, cad4, asrc, adst, N, 4, 64);
  agg4_k<<<agg_blocks, TB, 0, stream>>>(h_lin, asrc, adst, row_ptr, esrc, cb4, h_agg, N);

  hipMemsetAsync(fp, 0, 8 * 64 * 4, stream);
  pool_k<<<32, TB, 0, stream>>>(h_agg, fidx, flagg, fp, M);
  final_k<<<1, 512, 0, stream>>>(fp, h_agg, dec, cWp, cWt, cWo, cbo, d_out, dflag);
}

// Round 5
// 460.162 us; speedup vs baseline: 1.4254x; 1.0618x over previous
//
#include <hip/hip_runtime.h>
#include <hip/hip_bf16.h>
#include <math.h>

typedef __hip_bfloat16 bf16;

__device__ __forceinline__ float b2f(bf16 v){ return __bfloat162float(v); }
__device__ __forceinline__ float eluf(float x){ return x > 0.f ? x : __expf(x) - 1.f; }
__device__ __forceinline__ float lrelu(float x){ return x > 0.f ? x : 0.2f * x; }

// ---------------- dtype detection ----------------
// flag: 0 = bf16 inputs, 1 = fp32 inputs. (Round-2 evidence: bf16.)
__global__ void detect_k(const unsigned short* __restrict__ u16, int n, int* __restrict__ flag){
  int bad = 0;
  for (int k = threadIdx.x; k < n; k += 256){
    int ex = (u16[k] >> 7) & 0xFF;
    if (ex >= 0xC6) bad = 1;
  }
  if (__any(bad) && (threadIdx.x & 63) == 0) atomicOr(flag, 1);
}

// ---------------- unified input conversion to fp32 ----------------
struct ConvDesc {
  const void* src[21];
  int off[22];
};

__global__ void convert_all_k(ConvDesc d, float* __restrict__ out,
                              const int* __restrict__ flag, int total){
  int i = blockIdx.x * blockDim.x + threadIdx.x;
  if (i >= total) return;
  int a = 0;
  while (i >= d.off[a + 1]) ++a;
  int j = i - d.off[a];
  float v;
  if (*flag) v = ((const float*)d.src[a])[j];
  else       v = b2f(((const bf16*)d.src[a])[j]);
  out[i] = v;
}

// ---------------- CSR build (dst identical for all 4 layers) ----------------

__global__ void count_edges_k(const int* __restrict__ ei, int* __restrict__ counts, int E, int n){
  int e = blockIdx.x * blockDim.x + threadIdx.x;
  if (e >= E + n) return;
  int d = (e < E) ? ei[E + e] : (e - E);
  atomicAdd(&counts[d], 1);
}

__global__ void scan_k(const int* __restrict__ counts, int* __restrict__ row_ptr, int n){
  __shared__ int psum[1024];
  int t = threadIdx.x;
  int chunk = (n + 1023) >> 10;
  int beg = t * chunk;
  int end = beg + chunk; if (end > n) end = n;
  int s = 0;
  for (int i = beg; i < end; ++i) s += counts[i];
  psum[t] = s;
  __syncthreads();
  for (int off = 1; off < 1024; off <<= 1){
    int v = (t >= off) ? psum[t - off] : 0;
    __syncthreads();
    psum[t] += v;
    __syncthreads();
  }
  int run = psum[t] - s;
  for (int i = beg; i < end; ++i){ row_ptr[i] = run; run += counts[i]; }
  if (beg < n && end == n) row_ptr[n] = run;
}

__global__ void scatter_k(const int* __restrict__ ei, const int* __restrict__ row_ptr,
                          int* __restrict__ fill, int* __restrict__ esrc, int E, int n){
  int e = blockIdx.x * blockDim.x + threadIdx.x;
  if (e >= E + n) return;
  int s, d;
  if (e < E){ s = ei[e]; d = ei[E + e]; } else { s = e - E; d = s; }
  int pos = row_ptr[d] + atomicAdd(&fill[d], 1);
  esrc[pos] = s;
}

// ---------------- tiled linear with W in LDS ----------------
template<int K, int M, int MB>
__global__ void linear_w_k(const float* __restrict__ X, const float* __restrict__ W,
                           float* __restrict__ Y, int n){
  constexpr int MQ  = MB / 4;
  constexpr int NPW = 64 / MQ;
  constexpr int ITERS = 64 / (4 * NPW);
  __shared__ float wl[K * MB];
  __shared__ float xt[K][65];
  int base = blockIdx.x * 64;
  int mb0  = blockIdx.y * MB;
  int t = threadIdx.x;
  for (int q = t; q < K * MQ; q += 256){
    int k = q / MQ, j = q - k * MQ;
    ((float4*)wl)[q] = ((const float4*)(W + (size_t)k * M + mb0))[j];
  }
  for (int q = t; q < 64 * (K / 4); q += 256){
    int node = q / (K / 4);
    int k4 = q - node * (K / 4);
    float4 v = make_float4(0.f, 0.f, 0.f, 0.f);
    if (base + node < n) v = ((const float4*)(X + (size_t)(base + node) * K))[k4];
    xt[k4 * 4 + 0][node] = v.x;
    xt[k4 * 4 + 1][node] = v.y;
    xt[k4 * 4 + 2][node] = v.z;
    xt[k4 * 4 + 3][node] = v.w;
  }
  __syncthreads();
  int lane = t & 63, wv = t >> 6;
  int jj = lane % MQ;
  int no = lane / MQ;
#pragma unroll
  for (int it = 0; it < ITERS; ++it){
    int nl = (it * 4 + wv) * NPW + no;
    float ax = 0.f, ay = 0.f, az = 0.f, aw = 0.f;
#pragma unroll 8
    for (int k = 0; k < K; ++k){
      float xv = xt[k][nl];
      float4 w = ((const float4*)wl)[k * MQ + jj];
      ax += xv * w.x; ay += xv * w.y; az += xv * w.z; aw += xv * w.w;
    }
    int node = base + nl;
    if (node < n)
      ((float4*)(Y + (size_t)node * M + mb0))[jj] = make_float4(ax, ay, az, aw);
  }
}

// asrc[n*H+h] = dot(h[n,h,:], a_src[h,:]); float4 loads. (layers 1-3)
__global__ void alpha_k(const float* __restrict__ hlin, const float* __restrict__ a_src,
                        const float* __restrict__ a_dst, float* __restrict__ asrc,
                        float* __restrict__ adst, int n, int H, int C){
  int i = blockIdx.x * blockDim.x + threadIdx.x;
  if (i >= n * H) return;
  int node = i / H;
  int head = i - node * H;
  const float4* hp  = (const float4*)(hlin + (size_t)node * H * C + head * C);
  const float4* asp = (const float4*)(a_src + head * C);
  const float4* adp = (const float4*)(a_dst + head * C);
  float s1 = 0.f, s2 = 0.f;
  for (int c = 0; c < C / 4; ++c){
    float4 v = hp[c], a = asp[c], d = adp[c];
    s1 += v.x * a.x + v.y * a.y + v.z * a.z + v.w * a.w;
    s2 += v.x * d.x + v.y * d.y + v.z * d.z + v.w * d.w;
  }
  asrc[i] = s1;
  adst[i] = s2;
}

// ---------------- layer-4 algebraic restructure ----------------
// av[h*64+k] = sum_c W4[k, h*64+c] * a4[h,c]   (fold W4 into attention vecs)
__global__ void av_k(const float* __restrict__ W4, const float* __restrict__ as4,
                     const float* __restrict__ ad4, float* __restrict__ avs,
                     float* __restrict__ avd){
  int t = threadIdx.x;            // t = h*64+k
  int h = t >> 6, k = t & 63;
  const float* wr = W4 + (size_t)k * 256 + h * 64;
  const float* sr = as4 + h * 64;
  const float* dr = ad4 + h * 64;
  float s1 = 0.f, s2 = 0.f;
  for (int c = 0; c < 64; ++c){ float w = wr[c]; s1 += w * sr[c]; s2 += w * dr[c]; }
  avs[t] = s1;
  avd[t] = s2;
}

// alpha4 from h3 directly: asrc[n*4+h] = h3[n,:] . avs[h,:]
__global__ void alpha4_k(const float* __restrict__ h3, const float* __restrict__ avs,
                         const float* __restrict__ avd, float* __restrict__ asrc,
                         float* __restrict__ adst, int n){
  int i = blockIdx.x * blockDim.x + threadIdx.x;
  if (i >= n * 4) return;
  int node = i >> 2, head = i & 3;
  const float4* hp = (const float4*)(h3 + (size_t)node * 64);
  const float4* sp = (const float4*)(avs + head * 64);
  const float4* dp = (const float4*)(avd + head * 64);
  float s1 = 0.f, s2 = 0.f;
#pragma unroll 4
  for (int q = 0; q < 16; ++q){
    float4 v = hp[q], a = sp[q], d = dp[q];
    s1 += v.x * a.x + v.y * a.y + v.z * a.z + v.w * a.w;
    s2 += v.x * d.x + v.y * d.y + v.z * d.z + v.w * d.w;
  }
  asrc[i] = s1;
  adst[i] = s2;
}

// Layer 4 fused: gather h3 rows (256B/edge, was 1KB of h4), per-head weighted
// accumulate, then in-wave 256->64 matmul vs W4 (streamed, L2-resident),
// bias + elu.  out = mean_h ( (sum_e w_e h3[s_e]) @ W4_h / sw_h ) + b.
__global__ void agg4c_k(const float* __restrict__ h3, const float* __restrict__ asrc,
                        const float* __restrict__ adst, const int* __restrict__ row_ptr,
                        const int* __restrict__ esrc, const float* __restrict__ W4,
                        const float* __restrict__ bias, float* __restrict__ hout, int n){
  __shared__ float zt[4][256];
  int node = (blockIdx.x * blockDim.x + threadIdx.x) >> 6;
  if (node >= n) return;
  int lane = threadIdx.x & 63;
  int wv = (threadIdx.x >> 6) & 3;
  int head = lane >> 4;
  int j = lane & 15;
  int beg = row_ptr[node], end = row_ptr[node + 1];
  float4 adv = *(const float4*)(adst + (size_t)node * 4);
  float adm = head == 0 ? adv.x : head == 1 ? adv.y : head == 2 ? adv.z : adv.w;
  // pass 1: per-head max (16 lanes per head, strided edges)
  float m = -INFINITY;
  for (int p = beg + j; p < end; p += 16){
    int s = esrc[p];
    m = fmaxf(m, lrelu(asrc[s * 4 + head] + adm));
  }
  m = fmaxf(m, __shfl_xor(m, 1));
  m = fmaxf(m, __shfl_xor(m, 2));
  m = fmaxf(m, __shfl_xor(m, 4));
  m = fmaxf(m, __shfl_xor(m, 8));
  float mh0 = __shfl(m, 0), mh1 = __shfl(m, 16), mh2 = __shfl(m, 32), mh3 = __shfl(m, 48);
  // pass 2: weighted accumulate of h3 rows; lane owns channel c = lane
  float acc0 = 0.f, acc1 = 0.f, acc2 = 0.f, acc3 = 0.f;
  float sw0 = 0.f, sw1 = 0.f, sw2 = 0.f, sw3 = 0.f;
  for (int p = beg; p < end; ++p){
    int s = esrc[p];
    float4 a4 = *(const float4*)(asrc + (size_t)s * 4);
    float hv = h3[(size_t)s * 64 + lane];
    float w0 = __expf(lrelu(a4.x + adv.x) - mh0); sw0 += w0; acc0 += hv * w0;
    float w1 = __expf(lrelu(a4.y + adv.y) - mh1); sw1 += w1; acc1 += hv * w1;
    float w2 = __expf(lrelu(a4.z + adv.z) - mh2); sw2 += w2; acc2 += hv * w2;
    float w3 = __expf(lrelu(a4.w + adv.w) - mh3); sw3 += w3; acc3 += hv * w3;
  }
  // stage scaled accumulators: zt[h*64+c] = 0.25*acc_h[c]/sw_h  (same-wave LDS)
  zt[wv][lane]       = 0.25f * acc0 / sw0;
  zt[wv][64 + lane]  = 0.25f * acc1 / sw1;
  zt[wv][128 + lane] = 0.25f * acc2 / sw2;
  zt[wv][192 + lane] = 0.25f * acc3 / sw3;
  // in-wave matmul: out[c'] = sum_{c,h} zt[h*64+c] * W4[c, h*64+c']
  float out = 0.f;
#pragma unroll 4
  for (int c = 0; c < 64; ++c){
    const float* wr = W4 + (size_t)c * 256 + lane;
    float z0 = zt[wv][c], z1 = zt[wv][64 + c], z2 = zt[wv][128 + c], z3 = zt[wv][192 + c];
    out += z0 * wr[0] + z1 * wr[64] + z2 * wr[128] + z3 * wr[192];
  }
  hout[(size_t)node * 64 + lane] = eluf(out + bias[lane]);
}

// Layers 1-3: H=8, C=8. One wave per dst node; lane = head*8+j = channel.
__global__ void agg8_k(const float* __restrict__ hlin, const float* __restrict__ asrc,
                       const float* __restrict__ adst, const int* __restrict__ row_ptr,
                       const int* __restrict__ esrc, const float* __restrict__ bias,
                       float* __restrict__ hout, int n){
  int node = (blockIdx.x * blockDim.x + threadIdx.x) >> 6;
  if (node >= n) return;
  int lane = threadIdx.x & 63;
  int head = lane >> 3;
  int j = lane & 7;
  int beg = row_ptr[node], end = row_ptr[node + 1];
  float ad = adst[node * 8 + head];
  float m = -INFINITY;
  for (int p = beg + j; p < end; p += 8){
    int s = esrc[p];
    m = fmaxf(m, lrelu(asrc[s * 8 + head] + ad));
  }
  m = fmaxf(m, __shfl_xor(m, 1));
  m = fmaxf(m, __shfl_xor(m, 2));
  m = fmaxf(m, __shfl_xor(m, 4));
  float acc = 0.f, sw = 0.f;
  for (int p = beg; p < end; ++p){
    int s = esrc[p];
    float w = __expf(lrelu(asrc[s * 8 + head] + ad) - m);
    sw += w;
    acc += hlin[(size_t)s * 64 + lane] * w;
  }
  float o = acc / sw + bias[lane];
  hout[(size_t)node * 64 + lane] = eluf(o);
}

// ---------------- pooling + head ----------------

__global__ void pool_k(const float* __restrict__ h, const int* __restrict__ fidx,
                       const int* __restrict__ flag_arr, float* __restrict__ fp, int m){
  __shared__ float acc[512];
  for (int t = threadIdx.x; t < 512; t += blockDim.x) acc[t] = 0.f;
  __syncthreads();
  int lane = threadIdx.x & 63;
  int wave = (blockIdx.x * blockDim.x + threadIdx.x) >> 6;
  int nwaves = (gridDim.x * blockDim.x) >> 6;
  for (int i = wave; i < m; i += nwaves){
    int g = flag_arr[i];
    int node = fidx[i];
    atomicAdd(&acc[g * 64 + lane], h[(size_t)node * 64 + lane]);
  }
  __syncthreads();
  for (int t = threadIdx.x; t < 512; t += blockDim.x)
    atomicAdd(&fp[t], acc[t]);
}

__global__ void final_k(const float* __restrict__ fp, const float* __restrict__ h,
                        const int* __restrict__ dec,
                        const float* __restrict__ Wp, const float* __restrict__ Wt,
                        const float* __restrict__ Wo, const float* __restrict__ bo,
                        void* __restrict__ out, const int* __restrict__ dflag){
  int g = threadIdx.x >> 6;
  int j = threadIdx.x & 63;
  const float* fr = fp + g * 64;
  const float* tr = h + (size_t)dec[g] * 64;
  float a = 0.f, b = 0.f;
  for (int k = 0; k < 64; ++k){
    a += fr[k] * Wp[k * 64 + j];
    b += tr[k] * Wt[k * 64 + j];
  }
  float v = eluf(a) * Wo[j] + eluf(b) * Wo[64 + j];
  for (int off = 32; off > 0; off >>= 1) v += __shfl_down(v, off);
  if (j == 0){
    float r = v + bo[0];
    if (*dflag) ((float*)out)[g] = r;
    else        ((bf16*)out)[g] = __float2bfloat16(r);
  }
}

// ---------------- launch ----------------

extern "C" void kernel_launch(void* const* d_in, const int* in_sizes, int n_in,
                              void* d_out, int out_size, void* d_ws, size_t ws_size,
                              hipStream_t stream) {
  const int*  ei    = (const int*)d_in[1];
  const int*  fidx  = (const int*)d_in[2];
  const int*  flagg = (const int*)d_in[3];
  const int*  dec   = (const int*)d_in[4];

  const int N = in_sizes[0] / 16;   // 20000
  const int E = in_sizes[1] / 2;    // 320000
  const int M = in_sizes[2];        // 8000
  const int ET = E + N;

  const int fidxs[21] = {0,5,6,7,8,9,10,11,12,13,14,15,16,17,18,19,20,21,22,23,24};
  ConvDesc cd;
  int tot = 0;
  for (int k = 0; k < 21; ++k){
    cd.src[k] = d_in[fidxs[k]];
    cd.off[k] = tot;
    tot += in_sizes[fidxs[k]];
  }
  cd.off[21] = tot;

  char* p = (char*)d_ws;
  auto carve = [&](size_t bytes) -> void* {
    void* r = (void*)p;
    p += (bytes + 255) & ~(size_t)255;
    return r;
  };
  int*   dflag   = (int*)carve(4);
  float* conv    = (float*)carve((size_t)tot * 4);
  float* h_lin   = (float*)carve((size_t)N * 256 * 4);
  float* h_agg   = (float*)carve((size_t)N * 64 * 4);
  float* asrc    = (float*)carve((size_t)N * 8 * 4);
  float* adst    = (float*)carve((size_t)N * 8 * 4);
  int*   counts  = (int*)carve((size_t)N * 4);
  int*   row_ptr = (int*)carve((size_t)(N + 1) * 4);
  int*   esrc    = (int*)carve((size_t)ET * 4);
  float* fp      = (float*)carve(8 * 64 * 4);
  float* avs     = (float*)carve(256 * 4);
  float* avd     = (float*)carve(256 * 4);

  if ((size_t)(p - (char*)d_ws) > ws_size) return;

  const float* cW1 = conv + cd.off[1],  *cas1 = conv + cd.off[2],  *cad1 = conv + cd.off[3],  *cb1 = conv + cd.off[4];
  const float* cW2 = conv + cd.off[5],  *cas2 = conv + cd.off[6],  *cad2 = conv + cd.off[7],  *cb2 = conv + cd.off[8];
  const float* cW3 = conv + cd.off[9],  *cas3 = conv + cd.off[10], *cad3 = conv + cd.off[11], *cb3 = conv + cd.off[12];
  const float* cW4 = conv + cd.off[13], *cas4 = conv + cd.off[14], *cad4 = conv + cd.off[15], *cb4 = conv + cd.off[16];
  const float* cWp = conv + cd.off[17], *cWt = conv + cd.off[18], *cWo = conv + cd.off[19], *cbo = conv + cd.off[20];
  const float* xf  = conv + cd.off[0];

  const int TB = 256;

  hipMemsetAsync(dflag, 0, 4, stream);
  int nprobe = in_sizes[0] < 4096 ? in_sizes[0] : 4096;
  detect_k<<<1, TB, 0, stream>>>((const unsigned short*)d_in[0], nprobe, dflag);
  convert_all_k<<<(tot + TB - 1) / TB, TB, 0, stream>>>(cd, conv, dflag, tot);

  int eb = (ET + TB - 1) / TB;
  hipMemsetAsync(counts, 0, (size_t)N * 4, stream);
  count_edges_k<<<eb, TB, 0, stream>>>(ei, counts, E, N);
  scan_k<<<1, 1024, 0, stream>>>(counts, row_ptr, N);
  hipMemsetAsync(counts, 0, (size_t)N * 4, stream);
  scatter_k<<<eb, TB, 0, stream>>>(ei, row_ptr, counts, esrc, E, N);

  int agg_blocks = (N * 64 + TB - 1) / TB;
  int lin_blocks = (N + 63) / 64;

  // layer 1: 16 -> 8x8
  linear_w_k<16, 64, 64><<<dim3(lin_blocks, 1), TB, 0, stream>>>(xf, cW1, h_lin, N);
  alpha_k<<<(N * 8 + TB - 1) / TB, TB, 0, stream>>>(h_lin, cas1, cad1, asrc, adst, N, 8, 8);
  agg8_k<<<agg_blocks, TB, 0, stream>>>(h_lin, asrc, adst, row_ptr, esrc, cb1, h_agg, N);

  // layer 2
  linear_w_k<64, 64, 64><<<dim3(lin_blocks, 1), TB, 0, stream>>>(h_agg, cW2, h_lin, N);
  alpha_k<<<(N * 8 + TB - 1) / TB, TB, 0, stream>>>(h_lin, cas2, cad2, asrc, adst, N, 8, 8);
  agg8_k<<<agg_blocks, TB, 0, stream>>>(h_lin, asrc, adst, row_ptr, esrc, cb2, h_agg, N);

  // layer 3
  linear_w_k<64, 64, 64><<<dim3(lin_blocks, 1), TB, 0, stream>>>(h_agg, cW3, h_lin, N);
  alpha_k<<<(N * 8 + TB - 1) / TB, TB, 0, stream>>>(h_lin, cas3, cad3, asrc, adst, N, 8, 8);
  agg8_k<<<agg_blocks, TB, 0, stream>>>(h_lin, asrc, adst, row_ptr, esrc, cb3, h_agg, N);

  // layer 4 (algebraic): no h4 materialization
  av_k<<<1, 256, 0, stream>>>(cW4, cas4, cad4, avs, avd);
  alpha4_k<<<(N * 4 + TB - 1) / TB, TB, 0, stream>>>(h_agg, avs, avd, asrc, adst, N);
  agg4c_k<<<agg_blocks, TB, 0, stream>>>(h_agg, asrc, adst, row_ptr, esrc, cW4, cb4, h_lin, N);

  hipMemsetAsync(fp, 0, 8 * 64 * 4, stream);
  pool_k<<<64, TB, 0, stream>>>(h_lin, fidx, flagg, fp, M);
  final_k<<<1, 512, 0, stream>>>(fp, h_lin, dec, cWp, cWt, cWo, cbo, d_out, dflag);
}